// Round 1
// baseline (450.356 us; speedup 1.0000x reference)
//
#include <hip/hip_runtime.h>
#include <math.h>

#define BB 4
#define NN 4096
#define HH 480
#define WW 640
#define RAD2 4.0f
#define TH_SCORE 0.1f
#define KPPEN -0.001f
#define MAXNBR 8
#define NMSTH 256

// ---------------- workspace layout (bytes) ----------------
// scores : 0        f32 [8][4096]            131072
// pts    : 131072   float4 [8][4096] (x,y,sq) 524288
// cnt    : 655360   i32 [8][4096]            131072
// nbr    : 786432   u16 [8][4096][8]         524288
// acc    : 1310720  f32 [2][4]               32
// total ~1.25 MB

__global__ __launch_bounds__(256) void k_sample(
    const float* __restrict__ lp0, const float* __restrict__ lp1,
    const float* __restrict__ kp0, const float* __restrict__ kp1,
    float* __restrict__ scores, float4* __restrict__ pts)
{
#pragma clang fp contract(off)
    int gid = blockIdx.x * 256 + threadIdx.x;   // 0..32767
    int s = gid >> 14;
    int r = gid & 16383;
    int b = r >> 12;
    const float* kp  = (s ? kp1 : kp0) + (size_t)r * 2;
    const float* img = (s ? lp1 : lp0) + (size_t)b * (HH * WW);
    float px = kp[0], py = kp[1];
    // grid_sample coords (align_corners=True), exactly as reference
    float x = (px + 1.0f) * 0.5f * (float)(WW - 1);
    float y = (py + 1.0f) * 0.5f * (float)(HH - 1);
    float x0 = floorf(x), y0 = floorf(y);
    float wx = x - x0, wy = y - y0;
    int ix0 = (int)fminf(fmaxf(x0, 0.0f), (float)(WW - 1));
    int iy0 = (int)fminf(fmaxf(y0, 0.0f), (float)(HH - 1));
    int ix1 = (int)fminf(fmaxf(x0 + 1.0f, 0.0f), (float)(WW - 1));
    int iy1 = (int)fminf(fmaxf(y0 + 1.0f, 0.0f), (float)(HH - 1));
    float g00 = img[iy0 * WW + ix0];
    float g01 = img[iy0 * WW + ix1];
    float g10 = img[iy1 * WW + ix0];
    float g11 = img[iy1 * WW + ix1];
    float sc = g00 * (1.0f - wx) * (1.0f - wy)
             + g01 * wx * (1.0f - wy)
             + g10 * (1.0f - wx) * wy
             + g11 * wx * wy;
    // pixel coords as in reference: (kp/2 + 0.5) * (W-1 | H-1)
    float xw = (px / 2.0f + 0.5f) * (float)(WW - 1);
    float yw = (py / 2.0f + 0.5f) * (float)(HH - 1);
    float xx = xw * xw;
    float yy = yw * yw;
    float sq = xx + yy;
    scores[gid] = sc;
    pts[gid] = make_float4(xw, yw, sq, 0.0f);
}

__global__ __launch_bounds__(256) void k_pairs(
    const float4* __restrict__ pts, int* __restrict__ cnt,
    unsigned short* __restrict__ nbr)
{
#pragma clang fp contract(off)
    __shared__ float4 sp[NN];   // 64 KB
    int img = blockIdx.x >> 4;
    int chunk = blockIdx.x & 15;
    const float4* p = pts + (size_t)img * NN;
    for (int t = threadIdx.x; t < NN; t += 256) sp[t] = p[t];
    __syncthreads();
    int i = chunk * 256 + threadIdx.x;
    float4 pi = sp[i];
    int c = 0;
    unsigned short* row = nbr + ((size_t)img * NN + i) * MAXNBR;
    for (int j = 0; j < NN; ++j) {
        float4 pj = sp[j];
        float dot = pi.x * pj.x + pi.y * pj.y;   // mul,mul,add (contract off)
        float t = pi.z + pj.z;
        float d2 = fmaf(-2.0f, dot, t);          // == t - 2*dot (2*dot exact)
        if (d2 < RAD2) { if (c < MAXNBR) row[c] = (unsigned short)j; ++c; }
    }
    cnt[(size_t)img * NN + i] = c;   // includes self, >= 1
}

// One block per image. Exact NMS: isolated pairs resolved in parallel
// (independent components); remaining need-points (components >=3, ~90/img)
// processed sequentially in ascending index, redundantly by all threads
// (all reads are identical LDS/global values -> deterministic, no races
// beyond benign same-value LDS writes).
__global__ __launch_bounds__(NMSTH) void k_nms(
    const float* __restrict__ scoresG, const float4* __restrict__ pts,
    const int* __restrict__ cntG, const unsigned short* __restrict__ nbrG,
    const float* __restrict__ dd0, const float* __restrict__ dd1,
    float* __restrict__ acc)
{
#pragma clang fp contract(off)
    __shared__ float          s_sc[NN];       // 16 KB
    __shared__ unsigned char  s_cnt[NN];      // 4 KB (clamped 255)
    __shared__ unsigned char  s_alive[NN];    // 4 KB
    __shared__ unsigned short s_seq[NN];      // 8 KB
    __shared__ int            s_cnts[NMSTH + 1];
    __shared__ float          s_rf[NMSTH];
    __shared__ int            s_ri[NMSTH];

    int img = blockIdx.x;
    int tid = threadIdx.x;
    int base = img * NN;
    const unsigned short* nb = nbrG + (size_t)base * MAXNBR;

    for (int t = tid; t < NN; t += NMSTH) {
        s_sc[t] = scoresG[base + t];
        int c = cntG[base + t];
        s_cnt[t] = (unsigned char)(c > 255 ? 255 : c);
        s_alive[t] = 1;
    }
    __syncthreads();

    // ---- phase 1: isolated pairs (both endpoints cnt==2), order-free ----
    for (int t = tid; t < NN; t += NMSTH) {
        if (s_cnt[t] == 2) {
            unsigned short e0 = nb[t * MAXNBR + 0];
            unsigned short e1 = nb[t * MAXNBR + 1];
            int j = (e0 == t) ? e1 : e0;
            if (s_cnt[j] == 2) {
                int lo = t < j ? t : j;
                int hi = t < j ? j : t;
                int winner = (s_sc[lo] >= s_sc[hi]) ? lo : hi;  // argmax, first-of-max
                int loser  = (winner == lo) ? hi : lo;
                s_alive[loser] = 0;   // same value written by both endpoints: benign
            }
        }
    }

    // ---- build ordered residual list: need && !pairtype ----
    int tb = tid * (NN / NMSTH);
    int lc = 0;
    for (int k = 0; k < NN / NMSTH; ++k) {
        int i = tb + k;
        int c = s_cnt[i];
        bool sq = false;
        if (c > 2) sq = true;
        else if (c == 2) {
            unsigned short e0 = nb[i * MAXNBR + 0];
            unsigned short e1 = nb[i * MAXNBR + 1];
            int j = (e0 == i) ? e1 : e0;
            if (s_cnt[j] != 2) sq = true;
        }
        lc += sq ? 1 : 0;
    }
    s_cnts[tid] = lc;
    __syncthreads();
    if (tid == 0) {
        int run = 0;
        for (int t = 0; t < NMSTH; ++t) { int v = s_cnts[t]; s_cnts[t] = run; run += v; }
        s_cnts[NMSTH] = run;
    }
    __syncthreads();
    {
        int off = s_cnts[tid];
        for (int k = 0; k < NN / NMSTH; ++k) {
            int i = tb + k;
            int c = s_cnt[i];
            bool sq = false;
            if (c > 2) sq = true;
            else if (c == 2) {
                unsigned short e0 = nb[i * MAXNBR + 0];
                unsigned short e1 = nb[i * MAXNBR + 1];
                int j = (e0 == i) ? e1 : e0;
                if (s_cnt[j] != 2) sq = true;
            }
            if (sq) s_seq[off++] = (unsigned short)i;
        }
    }
    __syncthreads();
    int seqn = s_cnts[NMSTH];

    // ---- phase 2: faithful sequential NMS on residual list ----
    for (int t = 0; t < seqn; ++t) {
        int i = s_seq[t];
        if (s_alive[i] == 0) continue;     // uniform: same LDS value for all
        int c = s_cnt[i];
        if (c <= MAXNBR) {
            int bi = -1; float bs = -1.0f;     // scores >= 0, row non-empty
            for (int k = 0; k < c; ++k) {
                int j = nb[i * MAXNBR + k];
                float sc = s_sc[j];
                if (sc > bs) { bs = sc; bi = j; }   // ascending j -> first max
            }
            for (int k = 0; k < c; ++k) {
                int j = nb[i * MAXNBR + k];
                if (j != bi) s_alive[j] = 0;
            }
        } else {
            // overflow (>8 neighbors) fallback: cooperative full row scan
            __syncthreads();
            float4 pi = pts[base + i];
            float bs = -1.0f; int bi = NN;
            for (int j = tid; j < NN; j += NMSTH) {
                float4 pj = pts[base + j];
                float dot = pi.x * pj.x + pi.y * pj.y;
                float tt = pi.z + pj.z;
                float d2 = fmaf(-2.0f, dot, tt);
                if (d2 < RAD2) {
                    float sc = s_sc[j];
                    if (sc > bs || (sc == bs && j < bi)) { bs = sc; bi = j; }
                }
            }
            s_rf[tid] = bs; s_ri[tid] = bi;
            __syncthreads();
            for (int st = NMSTH / 2; st > 0; st >>= 1) {
                if (tid < st) {
                    float os = s_rf[tid + st]; int oi = s_ri[tid + st];
                    if (os > s_rf[tid] || (os == s_rf[tid] && oi < s_ri[tid])) {
                        s_rf[tid] = os; s_ri[tid] = oi;
                    }
                }
                __syncthreads();
            }
            bi = s_ri[0];
            __syncthreads();
            for (int j = tid; j < NN; j += NMSTH) {
                float4 pj = pts[base + j];
                float dot = pi.x * pj.x + pi.y * pj.y;
                float tt = pi.z + pj.z;
                float d2 = fmaf(-2.0f, dot, tt);
                if (d2 < RAD2 && j != bi) s_alive[j] = 0;
            }
            __syncthreads();
        }
    }
    __syncthreads();

    // ---- final per-image partial sums ----
    int stream = img >> 2, b = img & 3;
    const float* disp = (stream ? dd1 : dd0) + (size_t)b * NN;
    float sum_dp = 0.f, cnt_p = 0.f, sum_sv = 0.f, cnt_v = 0.f;
    for (int t = tid; t < NN; t += NMSTH) {
        if (s_alive[t]) {
            float sc = s_sc[t];
            cnt_v += 1.0f; sum_sv += sc;
            if (sc > TH_SCORE) { cnt_p += 1.0f; sum_dp += disp[t]; }
        }
    }
    float vals0 = sum_dp, vals1 = cnt_p, vals2 = sum_sv, vals3 = cnt_v;
#pragma unroll
    for (int q = 0; q < 4; ++q) {
        float v = (q == 0) ? vals0 : (q == 1) ? vals1 : (q == 2) ? vals2 : vals3;
        for (int o = 32; o > 0; o >>= 1) v += __shfl_down(v, o, 64);
        if ((tid & 63) == 0) s_rf[tid >> 6] = v;
        __syncthreads();
        if (tid == 0) {
            float r = s_rf[0] + s_rf[1] + s_rf[2] + s_rf[3];
            atomicAdd(&acc[stream * 4 + q], r);
        }
        __syncthreads();
    }
}

__global__ void k_final(const float* __restrict__ acc, float* __restrict__ out)
{
    float r = 0.0f;
    for (int s = 0; s < 2; ++s) {
        float sdp = acc[s * 4 + 0], cp = acc[s * 4 + 1];
        float ssv = acc[s * 4 + 2], cv = acc[s * 4 + 3];
        r += sdp / fmaxf(cp, 1.0f) + KPPEN * (ssv / fmaxf(cv, 1.0f));
    }
    out[0] = r;
}

extern "C" void kernel_launch(void* const* d_in, const int* in_sizes, int n_in,
                              void* d_out, int out_size, void* d_ws, size_t ws_size,
                              hipStream_t stream)
{
    const float* lp0 = (const float*)d_in[0];
    const float* lp1 = (const float*)d_in[1];
    const float* kp0 = (const float*)d_in[2];
    const float* kp1 = (const float*)d_in[3];
    const float* dd0 = (const float*)d_in[4];
    const float* dd1 = (const float*)d_in[5];

    char* ws = (char*)d_ws;
    float*          scores = (float*)(ws + 0);
    float4*         pts    = (float4*)(ws + 131072);
    int*            cnt    = (int*)(ws + 655360);
    unsigned short* nbr    = (unsigned short*)(ws + 786432);
    float*          acc    = (float*)(ws + 1310720);

    hipMemsetAsync(acc, 0, 8 * sizeof(float), stream);
    k_sample<<<128, 256, 0, stream>>>(lp0, lp1, kp0, kp1, scores, pts);
    k_pairs<<<128, 256, 0, stream>>>(pts, cnt, nbr);
    k_nms<<<8, NMSTH, 0, stream>>>(scores, pts, cnt, nbr, dd0, dd1, acc);
    k_final<<<1, 1, 0, stream>>>(acc, (float*)d_out);
}

// Round 4
// 232.779 us; speedup vs baseline: 1.9347x; 1.9347x over previous
//
#include <hip/hip_runtime.h>
#include <math.h>

#define BB 4
#define NN 4096
#define HH 480
#define WW 640
#define RAD2 4.0f
#define TH_SCORE 0.1f
#define KPPEN -0.001f
#define MAXNBR 8
#define NMSTH 256

// ---------------- workspace layout (bytes) ----------------
#define OFF_SCORES 0        // f32 [8][4096]      131072
#define OFF_PTS    131072   // float4 [8][4096]   524288
#define OFF_CNT    655360   // i32 [8][4096]      131072
#define OFF_WLN    786432   // i32                4
#define OFF_ACC    786448   // f32 [2][4]         32
#define OFF_NBR    786560   // u16 [8][4096][8]   524288
#define OFF_WL     1310848  // i32 [32768]        131072
// zero region: [OFF_CNT, OFF_NBR) = 131200 bytes (cnt + wl_n + acc)

__global__ __launch_bounds__(256) void k_sample(
    const float* __restrict__ lp0, const float* __restrict__ lp1,
    const float* __restrict__ kp0, const float* __restrict__ kp1,
    float* __restrict__ scores, float4* __restrict__ pts)
{
#pragma clang fp contract(off)
    int gid = blockIdx.x * 256 + threadIdx.x;   // 0..32767
    int s = gid >> 14;
    int r = gid & 16383;
    int b = r >> 12;
    const float* kp  = (s ? kp1 : kp0) + (size_t)r * 2;
    const float* img = (s ? lp1 : lp0) + (size_t)b * (HH * WW);
    float px = kp[0], py = kp[1];
    float x = (px + 1.0f) * 0.5f * (float)(WW - 1);
    float y = (py + 1.0f) * 0.5f * (float)(HH - 1);
    float x0 = floorf(x), y0 = floorf(y);
    float wx = x - x0, wy = y - y0;
    int ix0 = (int)fminf(fmaxf(x0, 0.0f), (float)(WW - 1));
    int iy0 = (int)fminf(fmaxf(y0, 0.0f), (float)(HH - 1));
    int ix1 = (int)fminf(fmaxf(x0 + 1.0f, 0.0f), (float)(WW - 1));
    int iy1 = (int)fminf(fmaxf(y0 + 1.0f, 0.0f), (float)(HH - 1));
    float g00 = img[iy0 * WW + ix0];
    float g01 = img[iy0 * WW + ix1];
    float g10 = img[iy1 * WW + ix0];
    float g11 = img[iy1 * WW + ix1];
    float sc = g00 * (1.0f - wx) * (1.0f - wy)
             + g01 * wx * (1.0f - wy)
             + g10 * (1.0f - wx) * wy
             + g11 * wx * wy;
    float xw = (px / 2.0f + 0.5f) * (float)(WW - 1);
    float yw = (py / 2.0f + 0.5f) * (float)(HH - 1);
    float sq = xw * xw + yw * yw;
    scores[gid] = sc;
    pts[gid] = make_float4(xw, yw, sq, 0.0f);
}

// Count-only pass, j-split for occupancy. grid = 8 img * 16 ichunk * 8 jchunk
__global__ __launch_bounds__(256) void k_cnt(
    const float4* __restrict__ pts, int* __restrict__ cnt)
{
#pragma clang fp contract(off)
    __shared__ float4 sp[512];   // 8 KB j-chunk
    int bk = blockIdx.x;
    int img = bk >> 7;
    int ichunk = (bk >> 3) & 15;
    int jchunk = bk & 7;
    int i = (img << 12) + ichunk * 256 + threadIdx.x;
    int jbase = jchunk * 512;
    const float4* p = pts + ((size_t)img << 12);
    for (int t = threadIdx.x; t < 512; t += 256) sp[t] = p[jbase + t];
    float4 pi = pts[i];
    __syncthreads();
    int c = 0;
#pragma unroll 4
    for (int j = 0; j < 512; ++j) {
        float4 pj = sp[j];
        float dot = pi.x * pj.x + pi.y * pj.y;   // mul,mul,add (contract off)
        float t = pi.z + pj.z;
        float d2 = fmaf(-2.0f, dot, t);          // == t - 2*dot (2*dot exact)
        if (d2 < RAD2) ++c;
    }
    if (c > 0) atomicAdd(&cnt[i], c);
}

__global__ __launch_bounds__(256) void k_wl(
    const int* __restrict__ cnt, int* __restrict__ wl_n, int* __restrict__ wl)
{
    int i = blockIdx.x * 256 + threadIdx.x;
    if (cnt[i] >= 2) { int p = atomicAdd(wl_n, 1); wl[p] = i; }
}

// One wave per worklist point: ordered neighbor list via ballot compaction.
__global__ __launch_bounds__(256) void k_build(
    const float4* __restrict__ pts, const int* __restrict__ wl_n,
    const int* __restrict__ wl, unsigned short* __restrict__ nbr)
{
#pragma clang fp contract(off)
    int wave = blockIdx.x * 4 + (threadIdx.x >> 6);
    int lane = threadIdx.x & 63;
    int n = *wl_n;
    for (int t = wave; t < n; t += gridDim.x * 4) {
        int gi = wl[t];
        int img = gi >> 12;
        const float4* p = pts + ((size_t)img << 12);
        float4 pi = pts[gi];
        unsigned short* row = nbr + (size_t)gi * MAXNBR;
        int c = 0;
        for (int base = 0; base < NN; base += 64) {
            float4 pj = p[base + lane];
            float dot = pi.x * pj.x + pi.y * pj.y;
            float tt = pi.z + pj.z;
            float d2 = fmaf(-2.0f, dot, tt);
            bool hit = d2 < RAD2;
            unsigned long long m = __ballot(hit);
            if (hit) {
                int pos = c + __popcll(m & ((1ull << lane) - 1ull));
                if (pos < MAXNBR) row[pos] = (unsigned short)(base + lane);
            }
            c += __popcll(m);
        }
    }
}

// One block per image. Exact NMS: isolated pairs parallel; residual sequential
// on wave 0 (components >=3, ~80/img), all data staged in LDS.
__global__ __launch_bounds__(NMSTH) void k_nms(
    const float* __restrict__ scoresG, const float4* __restrict__ pts,
    const int* __restrict__ cntG, const unsigned short* __restrict__ nbrG,
    const float* __restrict__ dd0, const float* __restrict__ dd1,
    float* __restrict__ acc)
{
#pragma clang fp contract(off)
    __shared__ float          s_sc[NN];       // 16 KB
    __shared__ unsigned char  s_cnt[NN];      // 4 KB
    __shared__ unsigned char  s_alive[NN];    // 4 KB
    __shared__ unsigned short s_seq[NN];      // 8 KB
    __shared__ __align__(16) unsigned short s_nbr[512][MAXNBR]; // 8 KB
    __shared__ int            s_cnts[NMSTH + 1];
    __shared__ float          s_rf[NMSTH];

    int img = blockIdx.x;
    int tid = threadIdx.x;
    int base = img * NN;
    const unsigned short* nb = nbrG + (size_t)base * MAXNBR;

    for (int t = tid; t < NN; t += NMSTH) {
        s_sc[t] = scoresG[base + t];
        int c = cntG[base + t];
        s_cnt[t] = (unsigned char)(c > 255 ? 255 : c);
        s_alive[t] = 1;
    }
    __syncthreads();

    // ---- phase 1: isolated pairs (both endpoints cnt==2), order-free ----
    for (int t = tid; t < NN; t += NMSTH) {
        if (s_cnt[t] == 2) {
            unsigned short e0 = nb[t * MAXNBR + 0];
            unsigned short e1 = nb[t * MAXNBR + 1];
            int j = (e0 == t) ? e1 : e0;
            if (s_cnt[j] == 2) {
                int lo = t < j ? t : j;
                int hi = t < j ? j : t;
                int winner = (s_sc[lo] >= s_sc[hi]) ? lo : hi;
                int loser  = (winner == lo) ? hi : lo;
                s_alive[loser] = 0;
            }
        }
    }

    // ---- build ordered residual list: need && !pairtype ----
    int tb = tid * (NN / NMSTH);
    int lc = 0;
    for (int k = 0; k < NN / NMSTH; ++k) {
        int i = tb + k;
        int c = s_cnt[i];
        bool sq = false;
        if (c > 2) sq = true;
        else if (c == 2) {
            unsigned short e0 = nb[i * MAXNBR + 0];
            unsigned short e1 = nb[i * MAXNBR + 1];
            int j = (e0 == i) ? e1 : e0;
            if (s_cnt[j] != 2) sq = true;
        }
        lc += sq ? 1 : 0;
    }
    s_cnts[tid] = lc;
    __syncthreads();
    if (tid == 0) {
        int run = 0;
        for (int t = 0; t < NMSTH; ++t) { int v = s_cnts[t]; s_cnts[t] = run; run += v; }
        s_cnts[NMSTH] = run;
    }
    __syncthreads();
    {
        int off = s_cnts[tid];
        for (int k = 0; k < NN / NMSTH; ++k) {
            int i = tb + k;
            int c = s_cnt[i];
            bool sq = false;
            if (c > 2) sq = true;
            else if (c == 2) {
                unsigned short e0 = nb[i * MAXNBR + 0];
                unsigned short e1 = nb[i * MAXNBR + 1];
                int j = (e0 == i) ? e1 : e0;
                if (s_cnt[j] != 2) sq = true;
            }
            if (sq) s_seq[off++] = (unsigned short)i;
        }
    }
    __syncthreads();
    int seqn = s_cnts[NMSTH];

    // ---- stage residual neighbor rows into LDS ----
    int stagen = seqn < 512 ? seqn : 512;
    for (int t = tid; t < stagen; t += NMSTH) {
        int i = s_seq[t];
        *(uint4*)&s_nbr[t][0] = *(const uint4*)&nb[i * MAXNBR];
    }
    __syncthreads();

    // ---- phase 2: faithful sequential NMS, wave 0 only, LDS-resident ----
    if (tid < 64) {
        int lane = tid;
        for (int t = 0; t < seqn; ++t) {
            int i = s_seq[t];
            if (s_alive[i] == 0) continue;          // uniform within wave
            int c = s_cnt[i];
            if (c <= MAXNBR) {
                const unsigned short* rowp = (t < 512) ? &s_nbr[t][0]
                                                       : &nb[i * MAXNBR];
                int bi = -1; float bs = -1.0f;
                for (int k = 0; k < c; ++k) {
                    int j = rowp[k];
                    float sc = s_sc[j];
                    if (sc > bs) { bs = sc; bi = j; }   // ascending j -> first max
                }
                for (int k = 0; k < c; ++k) {
                    int j = rowp[k];
                    if (j != bi) s_alive[j] = 0;
                }
            } else {
                // overflow fallback: full row scan by the wave
                float4 pi = pts[base + i];
                float bs = -1.0f; int bi = NN;
                for (int j = lane; j < NN; j += 64) {
                    float4 pj = pts[base + j];
                    float dot = pi.x * pj.x + pi.y * pj.y;
                    float tt = pi.z + pj.z;
                    float d2 = fmaf(-2.0f, dot, tt);
                    if (d2 < RAD2) {
                        float sc = s_sc[j];
                        if (sc > bs || (sc == bs && j < bi)) { bs = sc; bi = j; }
                    }
                }
                for (int o = 32; o > 0; o >>= 1) {
                    float os = __shfl_down(bs, o, 64);
                    int   oi = __shfl_down(bi, o, 64);
                    if (os > bs || (os == bs && oi < bi)) { bs = os; bi = oi; }
                }
                bi = __shfl(bi, 0, 64);
                for (int j = lane; j < NN; j += 64) {
                    float4 pj = pts[base + j];
                    float dot = pi.x * pj.x + pi.y * pj.y;
                    float tt = pi.z + pj.z;
                    float d2 = fmaf(-2.0f, dot, tt);
                    if (d2 < RAD2 && j != bi) s_alive[j] = 0;
                }
            }
        }
    }
    __syncthreads();

    // ---- final per-image partial sums ----
    int stream = img >> 2, b = img & 3;
    const float* disp = (stream ? dd1 : dd0) + (size_t)b * NN;
    float sum_dp = 0.f, cnt_p = 0.f, sum_sv = 0.f, cnt_v = 0.f;
    for (int t = tid; t < NN; t += NMSTH) {
        if (s_alive[t]) {
            float sc = s_sc[t];
            cnt_v += 1.0f; sum_sv += sc;
            if (sc > TH_SCORE) { cnt_p += 1.0f; sum_dp += disp[t]; }
        }
    }
    float vals0 = sum_dp, vals1 = cnt_p, vals2 = sum_sv, vals3 = cnt_v;
#pragma unroll
    for (int q = 0; q < 4; ++q) {
        float v = (q == 0) ? vals0 : (q == 1) ? vals1 : (q == 2) ? vals2 : vals3;
        for (int o = 32; o > 0; o >>= 1) v += __shfl_down(v, o, 64);
        if ((tid & 63) == 0) s_rf[tid >> 6] = v;
        __syncthreads();
        if (tid == 0) {
            float r = s_rf[0] + s_rf[1] + s_rf[2] + s_rf[3];
            atomicAdd(&acc[stream * 4 + q], r);
        }
        __syncthreads();
    }
}

__global__ void k_final(const float* __restrict__ acc, float* __restrict__ out)
{
    float r = 0.0f;
    for (int s = 0; s < 2; ++s) {
        float sdp = acc[s * 4 + 0], cp = acc[s * 4 + 1];
        float ssv = acc[s * 4 + 2], cv = acc[s * 4 + 3];
        r += sdp / fmaxf(cp, 1.0f) + KPPEN * (ssv / fmaxf(cv, 1.0f));
    }
    out[0] = r;
}

extern "C" void kernel_launch(void* const* d_in, const int* in_sizes, int n_in,
                              void* d_out, int out_size, void* d_ws, size_t ws_size,
                              hipStream_t stream)
{
    const float* lp0 = (const float*)d_in[0];
    const float* lp1 = (const float*)d_in[1];
    const float* kp0 = (const float*)d_in[2];
    const float* kp1 = (const float*)d_in[3];
    const float* dd0 = (const float*)d_in[4];
    const float* dd1 = (const float*)d_in[5];

    char* ws = (char*)d_ws;
    float*          scores = (float*)(ws + OFF_SCORES);
    float4*         pts    = (float4*)(ws + OFF_PTS);
    int*            cnt    = (int*)(ws + OFF_CNT);
    int*            wl_n   = (int*)(ws + OFF_WLN);
    float*          acc    = (float*)(ws + OFF_ACC);
    unsigned short* nbr    = (unsigned short*)(ws + OFF_NBR);
    int*            wl     = (int*)(ws + OFF_WL);

    hipMemsetAsync(ws + OFF_CNT, 0, OFF_NBR - OFF_CNT, stream);
    k_sample<<<128, 256, 0, stream>>>(lp0, lp1, kp0, kp1, scores, pts);
    k_cnt<<<1024, 256, 0, stream>>>(pts, cnt);
    k_wl<<<128, 256, 0, stream>>>(cnt, wl_n, wl);
    k_build<<<256, 256, 0, stream>>>(pts, wl_n, wl, nbr);
    k_nms<<<8, NMSTH, 0, stream>>>(scores, pts, cnt, nbr, dd0, dd1, acc);
    k_final<<<1, 1, 0, stream>>>(acc, (float*)d_out);
}

// Round 5
// 204.451 us; speedup vs baseline: 2.2028x; 1.1386x over previous
//
#include <hip/hip_runtime.h>
#include <math.h>

#define NN 4096
#define HH 480
#define WW 640
#define RAD2 4.0f
#define TH_SCORE 0.1f
#define KPPEN -0.001f
#define MAXNBR 8
#define NMSTH 256
#define RESCAP 384

// ---------------- workspace layout (bytes) ----------------
#define OFF_SCORES  0        // f32 [8][4096]            131072
#define OFF_PTS     131072   // float4 [8][4096]         524288
#define OFF_PACKED  655360   // u32 [32768][8]           1048576 (consumed by k_wl)
#define OFF_NBR     655360   // u16 [8][4096][8] 524288  (REUSES packed region, written after)
#define OFF_CNT     1703936  // i32 [32768]              131072
#define OFF_PARTNER 1835008  // u16 [32768]              65536
#define OFF_WL      1900544  // i32 [8][4096]            131072
#define OFF_WLC     2031616  // i32 [8]                  32
#define OFF_ACC     2031648  // f32 [2][4]               32
// zero per call: [OFF_WLC, OFF_ACC+32) = 64 bytes

__global__ __launch_bounds__(256) void k_sample(
    const float* __restrict__ lp0, const float* __restrict__ lp1,
    const float* __restrict__ kp0, const float* __restrict__ kp1,
    float* __restrict__ scores, float4* __restrict__ pts)
{
#pragma clang fp contract(off)
    int gid = blockIdx.x * 256 + threadIdx.x;   // 0..32767
    int s = gid >> 14;
    int r = gid & 16383;
    int b = r >> 12;
    const float* kp  = (s ? kp1 : kp0) + (size_t)r * 2;
    const float* img = (s ? lp1 : lp0) + (size_t)b * (HH * WW);
    float px = kp[0], py = kp[1];
    float x = (px + 1.0f) * 0.5f * (float)(WW - 1);
    float y = (py + 1.0f) * 0.5f * (float)(HH - 1);
    float x0 = floorf(x), y0 = floorf(y);
    float wx = x - x0, wy = y - y0;
    int ix0 = (int)fminf(fmaxf(x0, 0.0f), (float)(WW - 1));
    int iy0 = (int)fminf(fmaxf(y0, 0.0f), (float)(HH - 1));
    int ix1 = (int)fminf(fmaxf(x0 + 1.0f, 0.0f), (float)(WW - 1));
    int iy1 = (int)fminf(fmaxf(y0 + 1.0f, 0.0f), (float)(HH - 1));
    float g00 = img[iy0 * WW + ix0];
    float g01 = img[iy0 * WW + ix1];
    float g10 = img[iy1 * WW + ix0];
    float g11 = img[iy1 * WW + ix1];
    float sc = g00 * (1.0f - wx) * (1.0f - wy)
             + g01 * wx * (1.0f - wy)
             + g10 * (1.0f - wx) * wy
             + g11 * wx * wy;
    float xw = (px / 2.0f + 0.5f) * (float)(WW - 1);
    float yw = (py / 2.0f + 0.5f) * (float)(HH - 1);
    float sq = xw * xw + yw * yw;
    scores[gid] = sc;
    pts[gid] = make_float4(xw, yw, sq, 0.0f);
}

// Pair pass: per (img, ichunk-of-512, jchunk-of-512): counts + sum of hit j's.
// packed word = (sum_local_j << 10) | chunk_count.  grid = 8*8*8 = 512 blocks.
__global__ __launch_bounds__(256) void k_cnt(
    const float4* __restrict__ pts, unsigned int* __restrict__ packed)
{
#pragma clang fp contract(off)
    __shared__ float4 sp[512];
    int bk = blockIdx.x;
    int img = bk >> 6;
    int ich = (bk >> 3) & 7;
    int jc  = bk & 7;
    const float4* p = pts + ((size_t)img << 12);
    int jbase = jc << 9;
    for (int t = threadIdx.x; t < 512; t += 256) sp[t] = p[jbase + t];
    int i0 = (ich << 9) + threadIdx.x;
    int i1 = i0 + 256;
    float4 a = p[i0], b = p[i1];
    __syncthreads();
    int c0 = 0, c1 = 0, s0 = 0, s1 = 0;
#pragma unroll 4
    for (int j = 0; j < 512; ++j) {
        float4 q = sp[j];
        float dot0 = a.x * q.x + a.y * q.y;   // mul,mul,add (contract off)
        float t0 = a.z + q.z;
        float d20 = fmaf(-2.0f, dot0, t0);    // == t - 2*dot (2*dot exact)
        if (d20 < RAD2) { c0++; s0 += j; }
        float dot1 = b.x * q.x + b.y * q.y;
        float t1 = b.z + q.z;
        float d21 = fmaf(-2.0f, dot1, t1);
        if (d21 < RAD2) { c1++; s1 += j; }
    }
    size_t g0 = ((size_t)img << 12) + i0, g1 = ((size_t)img << 12) + i1;
    packed[g0 * 8 + jc] = ((unsigned)s0 << 10) | (unsigned)c0;
    packed[g1 * 8 + jc] = ((unsigned)s1 << 10) | (unsigned)c1;
}

// Reduce partials: total cnt, arithmetic partner (valid iff cnt==2), worklist of cnt>=3.
__global__ __launch_bounds__(256) void k_wl(
    const unsigned int* __restrict__ packed, int* __restrict__ cnt,
    unsigned short* __restrict__ partner, int* __restrict__ wlc,
    int* __restrict__ wl)
{
    int gid = blockIdx.x * 256 + threadIdx.x;
    const uint4* pk = (const uint4*)(packed + (size_t)gid * 8);
    uint4 v0 = pk[0], v1 = pk[1];
    unsigned int vs[8] = { v0.x, v0.y, v0.z, v0.w, v1.x, v1.y, v1.z, v1.w };
    int c = 0, sum = 0;
#pragma unroll
    for (int jc = 0; jc < 8; ++jc) {
        int cc = (int)(vs[jc] & 1023u);
        int sl = (int)(vs[jc] >> 10);
        c += cc;
        sum += sl + (jc << 9) * cc;   // globalize chunk-local j sums
    }
    int il = gid & (NN - 1);
    cnt[gid] = c;
    partner[gid] = (unsigned short)(sum - il);   // cnt==2: sum = il + partner
    if (c >= 3) {
        int img = gid >> 12;
        int pos = atomicAdd(&wlc[img], 1);
        wl[(img << 12) + pos] = il;
    }
}

// Ordered neighbor rows (ascending j, incl. self) for cnt>=3 points only (~55/img).
// grid = 8 img * 4 blocks; full image pts staged in 64KB LDS.
__global__ __launch_bounds__(256) void k_build(
    const float4* __restrict__ pts, const int* __restrict__ wlc,
    const int* __restrict__ wl, unsigned short* __restrict__ nbr)
{
#pragma clang fp contract(off)
    __shared__ float4 sp[NN];   // 64 KB
    int img = blockIdx.x >> 2;
    int sub = blockIdx.x & 3;
    const float4* p = pts + ((size_t)img << 12);
    for (int t = threadIdx.x; t < NN; t += 256) sp[t] = p[t];
    int n = wlc[img];
    __syncthreads();
    int wave = sub * 4 + (threadIdx.x >> 6);
    int lane = threadIdx.x & 63;
    for (int t = wave; t < n; t += 16) {
        int i = wl[(img << 12) + t];
        float4 pi = sp[i];
        unsigned short* row = nbr + (((size_t)img << 12) + i) * MAXNBR;
        int c = 0;
        for (int base = 0; base < NN; base += 64) {
            float4 pj = sp[base + lane];
            float dot = pi.x * pj.x + pi.y * pj.y;
            float tt = pi.z + pj.z;
            float d2 = fmaf(-2.0f, dot, tt);
            bool hit = d2 < RAD2;
            unsigned long long m = __ballot(hit);
            if (hit) {
                int pos = c + __popcll(m & ((1ull << lane) - 1ull));
                if (pos < MAXNBR) row[pos] = (unsigned short)(base + lane);
            }
            c += __popcll(m);
        }
    }
}

// One block per image. Exact NMS via component-parallel replay:
//  - phase 1: isolated pairs (both cnt==2), order-free
//  - residual = need && !pairtype; all residual neighbors are residual
//  - static winners precomputed in parallel (row & scores never change)
//  - min-label components; one owner thread replays each component in
//    ascending index => exactly the reference fori_loop semantics
__global__ __launch_bounds__(NMSTH) void k_nms(
    const float* __restrict__ scoresG, const float4* __restrict__ pts,
    const int* __restrict__ cntG, const unsigned short* __restrict__ partnerG,
    const unsigned short* __restrict__ nbrG,
    const float* __restrict__ dd0, const float* __restrict__ dd1,
    float* __restrict__ acc)
{
#pragma clang fp contract(off)
    __shared__ float          s_sc[NN];        // 16 KB
    __shared__ unsigned char  s_cnt[NN];       // 4 KB (clamped 255)
    __shared__ unsigned char  s_alive[NN];     // 4 KB
    __shared__ unsigned short s_partner[NN];   // 8 KB
    __shared__ unsigned short s_seq[NN];       // 8 KB
    __shared__ unsigned short s_lab[NN];       // 8 KB
    __shared__ __align__(16) unsigned short s_row[RESCAP][MAXNBR]; // 6 KB
    __shared__ float s_rx[RESCAP], s_ry[RESCAP], s_rz[RESCAP];     // 4.5 KB
    __shared__ unsigned short s_win[RESCAP];   // 768 B
    __shared__ unsigned short s_cnts[NMSTH + 1];
    __shared__ float s_rf[4];
    __shared__ int s_flag;

    int img = blockIdx.x, tid = threadIdx.x, base = img * NN;
    const unsigned short* nb = nbrG + (size_t)base * MAXNBR;

    for (int t = tid; t < NN; t += NMSTH) {
        s_sc[t] = scoresG[base + t];
        int c = cntG[base + t];
        s_cnt[t] = (unsigned char)(c > 255 ? 255 : c);
        s_partner[t] = partnerG[base + t];
        s_alive[t] = 1;
    }
    __syncthreads();

    // ---- phase 1: isolated pairs ----
    for (int t = tid; t < NN; t += NMSTH) {
        if (s_cnt[t] == 2) {
            int j = s_partner[t];
            if (s_cnt[j] == 2 && t < j) {
                int winner = (s_sc[t] >= s_sc[j]) ? t : j;  // tie -> lower idx
                s_alive[winner == t ? j : t] = 0;
            }
        }
    }

    // ---- ordered residual list ----
    int tb = tid * (NN / NMSTH);
    int lc = 0;
    for (int k = 0; k < NN / NMSTH; ++k) {
        int i = tb + k;
        int c = s_cnt[i];
        bool sq = (c > 2) || (c == 2 && s_cnt[s_partner[i]] != 2);
        lc += sq ? 1 : 0;
    }
    s_cnts[tid] = (unsigned short)lc;
    __syncthreads();
    if (tid == 0) {
        int run = 0;
        for (int t = 0; t < NMSTH; ++t) { int v = s_cnts[t]; s_cnts[t] = (unsigned short)run; run += v; }
        s_cnts[NMSTH] = (unsigned short)run;
    }
    __syncthreads();
    {
        int off = s_cnts[tid];
        for (int k = 0; k < NN / NMSTH; ++k) {
            int i = tb + k;
            int c = s_cnt[i];
            bool sq = (c > 2) || (c == 2 && s_cnt[s_partner[i]] != 2);
            if (sq) s_seq[off++] = (unsigned short)i;
        }
    }
    __syncthreads();
    int seqn = s_cnts[NMSTH];
    int stagen = seqn < RESCAP ? seqn : RESCAP;

    // ---- stage residual coords + rows ----
    for (int t = tid; t < stagen; t += NMSTH) {
        int p = s_seq[t];
        float4 pp = pts[base + p];
        s_rx[t] = pp.x; s_ry[t] = pp.y; s_rz[t] = pp.z;
        int c = s_cnt[p];
        if (c == 2) {
            int pr = s_partner[p];
            s_row[t][0] = (unsigned short)(p < pr ? p : pr);
            s_row[t][1] = (unsigned short)(p < pr ? pr : p);
        } else if (c <= MAXNBR) {
            *(uint4*)&s_row[t][0] = *(const uint4*)&nb[(size_t)p * MAXNBR];
        }
    }
    __syncthreads();

    auto get_xyz = [&](int u, int q, float& x, float& y, float& z) {
        if (u < RESCAP) { x = s_rx[u]; y = s_ry[u]; z = s_rz[u]; }
        else { float4 qq = pts[base + q]; x = qq.x; y = qq.y; z = qq.z; }
    };
    auto get_row = [&](int u, int q, int c, unsigned short* buf) -> const unsigned short* {
        if (u < RESCAP) return &s_row[u][0];
        if (c == 2) {
            int pr = s_partner[q];
            buf[0] = (unsigned short)(q < pr ? q : pr);
            buf[1] = (unsigned short)(q < pr ? pr : q);
            return buf;
        }
        return &nb[(size_t)q * MAXNBR];
    };

    // ---- static winners + label init ----
    for (int t = tid; t < seqn; t += NMSTH) {
        int p = s_seq[t];
        s_lab[p] = (unsigned short)p;
        int c = s_cnt[p];
        int win;
        if (c <= MAXNBR) {
            unsigned short buf[2];
            const unsigned short* rp = get_row(t, p, c, buf);
            float bs = -1.0f; int bi = p;
            for (int k = 0; k < c; ++k) {
                int j = rp[k];
                float sc = s_sc[j];
                if (sc > bs) { bs = sc; bi = j; }   // ascending j -> first max
            }
            win = bi;
        } else {
            // overflow: all neighbors are residual -> scan residual list
            float px, py, pz; get_xyz(t, p, px, py, pz);
            float bs = -1.0f; int bi = p;
            for (int u = 0; u < seqn; ++u) {
                int q = s_seq[u];
                float qx, qy, qz; get_xyz(u, q, qx, qy, qz);
                float dot = px * qx + py * qy;
                float tt = pz + qz;
                float d2 = fmaf(-2.0f, dot, tt);
                if (d2 < RAD2) {
                    float sc = s_sc[q];
                    if (sc > bs) { bs = sc; bi = q; }  // ascending u == ascending q
                }
            }
            win = bi;
        }
        if (t < RESCAP) s_win[t] = (unsigned short)win;
    }
    __syncthreads();

    // ---- min-label propagation to convergence (+ path halving) ----
    for (;;) {
        if (tid == 0) s_flag = 0;
        __syncthreads();
        for (int t = tid; t < seqn; t += NMSTH) {
            int p = s_seq[t];
            int m = s_lab[p];
            int c = s_cnt[p];
            if (c <= MAXNBR) {
                unsigned short buf[2];
                const unsigned short* rp = get_row(t, p, c, buf);
                for (int k = 0; k < c; ++k) { int l = s_lab[rp[k]]; if (l < m) m = l; }
            } else {
                float px, py, pz; get_xyz(t, p, px, py, pz);
                for (int u = 0; u < seqn; ++u) {
                    int q = s_seq[u];
                    float qx, qy, qz; get_xyz(u, q, qx, qy, qz);
                    float dot = px * qx + py * qy;
                    float tt = pz + qz;
                    float d2 = fmaf(-2.0f, dot, tt);
                    if (d2 < RAD2) { int l = s_lab[q]; if (l < m) m = l; }
                }
            }
            int h = s_lab[m]; if (h < m) m = h;   // path halving
            if (m < s_lab[p]) { s_lab[p] = (unsigned short)m; s_flag = 1; }
        }
        __syncthreads();
        bool done = (s_flag == 0);
        __syncthreads();
        if (done) break;
    }

    // ---- component-parallel exact replay (owner = min-index member) ----
    for (int t = tid; t < seqn; t += NMSTH) {
        int p = s_seq[t];
        if (s_lab[p] != (unsigned short)p) continue;   // owners only
        for (int u = 0; u < seqn; ++u) {
            int q = s_seq[u];
            if (s_lab[q] != (unsigned short)p) continue;  // not my member
            if (s_alive[q] == 0) continue;
            int c = s_cnt[q];
            if (c <= MAXNBR) {
                unsigned short buf[2];
                const unsigned short* rp = get_row(u, q, c, buf);
                int win = (u < RESCAP) ? s_win[u] : -1;
                if (win < 0) {   // recompute (only if u >= RESCAP)
                    float bs = -1.0f; int bi = q;
                    for (int k = 0; k < c; ++k) {
                        int j = rp[k]; float sc = s_sc[j];
                        if (sc > bs) { bs = sc; bi = j; }
                    }
                    win = bi;
                }
                for (int k = 0; k < c; ++k) {
                    int j = rp[k];
                    if (j != win) s_alive[j] = 0;
                }
            } else {
                int win;
                float px, py, pz; get_xyz(u, q, px, py, pz);
                {
                    float bs = -1.0f; int bi = q;
                    for (int v = 0; v < seqn; ++v) {
                        int r = s_seq[v];
                        float rx, ry, rz; get_xyz(v, r, rx, ry, rz);
                        float dot = px * rx + py * ry;
                        float tt = pz + rz;
                        float d2 = fmaf(-2.0f, dot, tt);
                        if (d2 < RAD2) { float sc = s_sc[r]; if (sc > bs) { bs = sc; bi = r; } }
                    }
                    win = (u < RESCAP) ? s_win[u] : bi;
                }
                for (int v = 0; v < seqn; ++v) {
                    int r = s_seq[v];
                    float rx, ry, rz; get_xyz(v, r, rx, ry, rz);
                    float dot = px * rx + py * ry;
                    float tt = pz + rz;
                    float d2 = fmaf(-2.0f, dot, tt);
                    if (d2 < RAD2 && r != win) s_alive[r] = 0;
                }
            }
        }
    }
    __syncthreads();

    // ---- final per-image partial sums ----
    int stream = img >> 2, b = img & 3;
    const float* disp = (stream ? dd1 : dd0) + (size_t)b * NN;
    float sum_dp = 0.f, cnt_p = 0.f, sum_sv = 0.f, cnt_v = 0.f;
    for (int t = tid; t < NN; t += NMSTH) {
        if (s_alive[t]) {
            float sc = s_sc[t];
            cnt_v += 1.0f; sum_sv += sc;
            if (sc > TH_SCORE) { cnt_p += 1.0f; sum_dp += disp[t]; }
        }
    }
#pragma unroll
    for (int q = 0; q < 4; ++q) {
        float v = (q == 0) ? sum_dp : (q == 1) ? cnt_p : (q == 2) ? sum_sv : cnt_v;
        for (int o = 32; o > 0; o >>= 1) v += __shfl_down(v, o, 64);
        if ((tid & 63) == 0) s_rf[tid >> 6] = v;
        __syncthreads();
        if (tid == 0) {
            float r = s_rf[0] + s_rf[1] + s_rf[2] + s_rf[3];
            atomicAdd(&acc[stream * 4 + q], r);
        }
        __syncthreads();
    }
}

__global__ void k_final(const float* __restrict__ acc, float* __restrict__ out)
{
    float r = 0.0f;
    for (int s = 0; s < 2; ++s) {
        float sdp = acc[s * 4 + 0], cp = acc[s * 4 + 1];
        float ssv = acc[s * 4 + 2], cv = acc[s * 4 + 3];
        r += sdp / fmaxf(cp, 1.0f) + KPPEN * (ssv / fmaxf(cv, 1.0f));
    }
    out[0] = r;
}

extern "C" void kernel_launch(void* const* d_in, const int* in_sizes, int n_in,
                              void* d_out, int out_size, void* d_ws, size_t ws_size,
                              hipStream_t stream)
{
    const float* lp0 = (const float*)d_in[0];
    const float* lp1 = (const float*)d_in[1];
    const float* kp0 = (const float*)d_in[2];
    const float* kp1 = (const float*)d_in[3];
    const float* dd0 = (const float*)d_in[4];
    const float* dd1 = (const float*)d_in[5];

    char* ws = (char*)d_ws;
    float*          scores  = (float*)(ws + OFF_SCORES);
    float4*         pts     = (float4*)(ws + OFF_PTS);
    unsigned int*   packed  = (unsigned int*)(ws + OFF_PACKED);
    unsigned short* nbr     = (unsigned short*)(ws + OFF_NBR);
    int*            cnt     = (int*)(ws + OFF_CNT);
    unsigned short* partner = (unsigned short*)(ws + OFF_PARTNER);
    int*            wl      = (int*)(ws + OFF_WL);
    int*            wlc     = (int*)(ws + OFF_WLC);
    float*          acc     = (float*)(ws + OFF_ACC);

    hipMemsetAsync(ws + OFF_WLC, 0, 64, stream);
    k_sample<<<128, 256, 0, stream>>>(lp0, lp1, kp0, kp1, scores, pts);
    k_cnt<<<512, 256, 0, stream>>>(pts, packed);
    k_wl<<<128, 256, 0, stream>>>(packed, cnt, partner, wlc, wl);
    k_build<<<32, 256, 0, stream>>>(pts, wlc, wl, nbr);
    k_nms<<<8, NMSTH, 0, stream>>>(scores, pts, cnt, partner, nbr, dd0, dd1, acc);
    k_final<<<1, 1, 0, stream>>>(acc, (float*)d_out);
}

// Round 6
// 135.378 us; speedup vs baseline: 3.3266x; 1.5102x over previous
//
#include <hip/hip_runtime.h>
#include <math.h>

#define NN 4096
#define HH 480
#define WW 640
#define RAD2 4.0f
#define TH_SCORE 0.1f
#define KPPEN -0.001f
#define CXN 160
#define CYN 120
#define NCELL (CXN * CYN)
#define SLOTS 8
#define CAP 48

// ---------------- workspace layout (bytes) ----------------
#define OFF_SCORES  0        // f32 [8][4096]               131072
#define OFF_PTS     131072   // float4 [8][4096]            524288
#define OFF_CNT     655360   // u8  [8][4096]               32768
#define OFF_PARTNER 688128   // u16 [8][4096]               65536
#define OFF_CELLS   753664   // u16 [8][19200][8]           2457600
#define OFF_CCNT    3211264  // u32 [8][19200]              614400
#define OFF_ACC     3825664  // f32 [2][4]                  32
// memset per call: [OFF_CCNT, OFF_ACC+32) = 614432 bytes (contiguous)

__device__ __forceinline__ int cell_of(float x, float y, int img) {
    int cx = (int)(x * 0.25f); cx = cx < 0 ? 0 : (cx > CXN - 1 ? CXN - 1 : cx);
    int cy = (int)(y * 0.25f); cy = cy < 0 ? 0 : (cy > CYN - 1 ? CYN - 1 : cy);
    return img * NCELL + cy * CXN + cx;
}

__global__ __launch_bounds__(256) void k_sample(
    const float* __restrict__ lp0, const float* __restrict__ lp1,
    const float* __restrict__ kp0, const float* __restrict__ kp1,
    float* __restrict__ scores, float4* __restrict__ pts,
    unsigned short* __restrict__ cells, unsigned int* __restrict__ ccnt)
{
#pragma clang fp contract(off)
    int gid = blockIdx.x * 256 + threadIdx.x;   // 0..32767
    int s = gid >> 14;
    int r = gid & 16383;
    int b = r >> 12;
    const float* kp  = (s ? kp1 : kp0) + (size_t)r * 2;
    const float* img = (s ? lp1 : lp0) + (size_t)b * (HH * WW);
    float px = kp[0], py = kp[1];
    float x = (px + 1.0f) * 0.5f * (float)(WW - 1);
    float y = (py + 1.0f) * 0.5f * (float)(HH - 1);
    float x0 = floorf(x), y0 = floorf(y);
    float wx = x - x0, wy = y - y0;
    int ix0 = (int)fminf(fmaxf(x0, 0.0f), (float)(WW - 1));
    int iy0 = (int)fminf(fmaxf(y0, 0.0f), (float)(HH - 1));
    int ix1 = (int)fminf(fmaxf(x0 + 1.0f, 0.0f), (float)(WW - 1));
    int iy1 = (int)fminf(fmaxf(y0 + 1.0f, 0.0f), (float)(HH - 1));
    float g00 = img[iy0 * WW + ix0];
    float g01 = img[iy0 * WW + ix1];
    float g10 = img[iy1 * WW + ix0];
    float g11 = img[iy1 * WW + ix1];
    float sc = g00 * (1.0f - wx) * (1.0f - wy)
             + g01 * wx * (1.0f - wy)
             + g10 * (1.0f - wx) * wy
             + g11 * wx * wy;
    float xw = (px / 2.0f + 0.5f) * (float)(WW - 1);
    float yw = (py / 2.0f + 0.5f) * (float)(HH - 1);
    float sq = xw * xw + yw * yw;   // mul, mul, add — matches all d2 users
    scores[gid] = sc;
    pts[gid] = make_float4(xw, yw, sq, 0.0f);
    int imgid = gid >> 12;          // 0..7
    int li = gid & (NN - 1);
    int cell = cell_of(xw, yw, imgid);
    unsigned int pos = atomicAdd(&ccnt[cell], 1u);
    if (pos < SLOTS) cells[(size_t)cell * SLOTS + pos] = (unsigned short)li;
}

// One thread per point: neighbor count + index-sum via 3x3 cell scan.
__global__ __launch_bounds__(256) void k_cnt(
    const float4* __restrict__ pts, const unsigned short* __restrict__ cells,
    const unsigned int* __restrict__ ccnt,
    unsigned char* __restrict__ cnt, unsigned short* __restrict__ partner)
{
#pragma clang fp contract(off)
    int gid = blockIdx.x * 256 + threadIdx.x;
    int imgid = gid >> 12;
    int li = gid & (NN - 1);
    const float4* p = pts + ((size_t)imgid << 12);
    float4 a = p[li];
    int cx = (int)(a.x * 0.25f); cx = cx < 0 ? 0 : (cx > CXN - 1 ? CXN - 1 : cx);
    int cy = (int)(a.y * 0.25f); cy = cy < 0 ? 0 : (cy > CYN - 1 ? CYN - 1 : cy);
    int c = 0, sum = 0; bool ov = false;
    for (int dy = -1; dy <= 1; ++dy) {
        int yy = cy + dy; if (yy < 0 || yy >= CYN) continue;
        for (int dx = -1; dx <= 1; ++dx) {
            int xx = cx + dx; if (xx < 0 || xx >= CXN) continue;
            int cell = imgid * NCELL + yy * CXN + xx;
            int n = (int)ccnt[cell];
            if (n > SLOTS) { ov = true; n = SLOTS; }
            for (int k = 0; k < n; ++k) {
                int q = cells[(size_t)cell * SLOTS + k];
                float4 qq = p[q];
                float dot = a.x * qq.x + a.y * qq.y;   // mul,mul,add (contract off)
                float t = a.z + qq.z;
                float d2 = fmaf(-2.0f, dot, t);        // == t - 2*dot (2*dot exact)
                if (d2 < RAD2) { ++c; sum += q; }
            }
        }
    }
    if (ov) {   // exact fallback (cell slot overflow; never in practice)
        c = 0; sum = 0;
        for (int j = 0; j < NN; ++j) {
            float4 qq = p[j];
            float dot = a.x * qq.x + a.y * qq.y;
            float t = a.z + qq.z;
            float d2 = fmaf(-2.0f, dot, t);
            if (d2 < RAD2) { ++c; sum += j; }
        }
    }
    cnt[gid] = (unsigned char)(c > 255 ? 255 : c);
    partner[gid] = (unsigned short)((sum - li) & 0xFFFF);  // valid iff c==2
}

// One THREAD per point. Exact NMS: alive[p] depends only on p's component.
// pair-type -> O(1); residual -> private BFS (LDS slice) + ascending replay.
__global__ __launch_bounds__(256) void k_nms(
    const float* __restrict__ scoresG, const float4* __restrict__ pts,
    const unsigned char* __restrict__ cntG, const unsigned short* __restrict__ partnerG,
    const unsigned short* __restrict__ cells, const unsigned int* __restrict__ ccnt,
    const float* __restrict__ dd0, const float* __restrict__ dd1,
    float* __restrict__ acc)
{
#pragma clang fp contract(off)
    __shared__ float          s_sc[NN];          // 16 KB
    __shared__ unsigned char  s_cnt[NN];         // 4 KB
    __shared__ unsigned short s_partner[NN];     // 8 KB
    __shared__ unsigned short s_mem[256][CAP + 2];  // 25.6 KB (pad: 25 words, gcd(25,32)=1)
    __shared__ unsigned short s_row[256][10];       // 5 KB  (pad: 5 words, gcd(5,32)=1)
    __shared__ float s_red[4];

    int imgid = blockIdx.x >> 4;
    int seg = blockIdx.x & 15;
    int base = imgid << 12;
    int tid = threadIdx.x;
    const float4* p = pts + (size_t)base;

    for (int t = tid; t < NN; t += 256) {
        s_sc[t] = scoresG[base + t];
        s_cnt[t] = cntG[base + t];
        s_partner[t] = partnerG[base + t];
    }
    __syncthreads();

    int li = (seg << 8) + tid;
    int c = s_cnt[li];
    bool alive = true;

    if (c >= 2) {
        int pr = s_partner[li];
        if (c == 2 && s_cnt[pr] == 2) {
            // isolated pair: survivor = argmax score, tie -> lower index
            int lo = li < pr ? li : pr, hi = li < pr ? pr : li;
            int w = (s_sc[lo] >= s_sc[hi]) ? lo : hi;
            alive = (w == li);
        } else {
            // ---- residual: BFS component (closed within residual set) ----
            unsigned short* mem = s_mem[tid];
            unsigned short* rb = s_row[tid];
            int cntm = 1, proc = 0;
            mem[0] = (unsigned short)li;
            auto insert = [&](int q) {
                for (int k = 0; k < cntm; ++k) if (mem[k] == (unsigned short)q) return;
                if (cntm < CAP) mem[cntm++] = (unsigned short)q;
            };
            // gather row of m from cells; returns count (<=8) in rb, or -1 => full scan
            auto gather = [&](int m, float4 pm) -> int {
                int gx = (int)(pm.x * 0.25f); gx = gx < 0 ? 0 : (gx > CXN - 1 ? CXN - 1 : gx);
                int gy = (int)(pm.y * 0.25f); gy = gy < 0 ? 0 : (gy > CYN - 1 ? CYN - 1 : gy);
                int rc = 0; bool ov = false;
                for (int dy = -1; dy <= 1; ++dy) {
                    int yy = gy + dy; if (yy < 0 || yy >= CYN) continue;
                    for (int dx = -1; dx <= 1; ++dx) {
                        int xx = gx + dx; if (xx < 0 || xx >= CXN) continue;
                        int cell = imgid * NCELL + yy * CXN + xx;
                        int n = (int)ccnt[cell];
                        if (n > SLOTS) { ov = true; n = SLOTS; }
                        for (int k = 0; k < n; ++k) {
                            int q = cells[(size_t)cell * SLOTS + k];
                            float4 qq = p[q];
                            float dot = pm.x * qq.x + pm.y * qq.y;
                            float t = pm.z + qq.z;
                            float d2 = fmaf(-2.0f, dot, t);
                            if (d2 < RAD2) { if (rc < 8) rb[rc] = (unsigned short)q; ++rc; }
                        }
                    }
                }
                return (ov || rc > 8) ? -1 : rc;
            };
            while (proc < cntm) {
                int m = mem[proc++];
                int cm = s_cnt[m];
                if (cm == 2) {
                    insert(s_partner[m]);
                } else if (cm <= 8) {
                    float4 pm = p[m];
                    int rc = gather(m, pm);
                    if (rc >= 0) {
                        for (int k = 0; k < rc; ++k) insert(rb[k]);
                    } else {
                        for (int j = 0; j < NN; ++j) {
                            float4 qq = p[j];
                            float dot = pm.x * qq.x + pm.y * qq.y;
                            float t = pm.z + qq.z;
                            float d2 = fmaf(-2.0f, dot, t);
                            if (d2 < RAD2) insert(j);
                        }
                    }
                } else {
                    float4 pm = p[m];
                    for (int j = 0; j < NN; ++j) {
                        float4 qq = p[j];
                        float dot = pm.x * qq.x + pm.y * qq.y;
                        float t = pm.z + qq.z;
                        float d2 = fmaf(-2.0f, dot, t);
                        if (d2 < RAD2) insert(j);
                    }
                }
            }
            // sort members ascending (insertion sort, small)
            for (int k = 1; k < cntm; ++k) {
                unsigned short v = mem[k]; int j2 = k;
                while (j2 > 0 && mem[j2 - 1] > v) { mem[j2] = mem[j2 - 1]; --j2; }
                mem[j2] = v;
            }
            // ---- ascending replay (exact reference semantics) ----
            unsigned long long am = (cntm >= 64) ? ~0ull : ((1ull << cntm) - 1ull);
            auto clearbit = [&](int q) {
                for (int k = 0; k < cntm; ++k)
                    if (mem[k] == (unsigned short)q) { am &= ~(1ull << k); return; }
            };
            for (int k = 0; k < cntm; ++k) {
                if (!((am >> k) & 1ull)) continue;
                int m = mem[k];
                int cm = s_cnt[m];
                if (cm == 2) {
                    int pr2 = s_partner[m];
                    int lo = m < pr2 ? m : pr2, hi = m < pr2 ? pr2 : m;
                    int w = (s_sc[lo] >= s_sc[hi]) ? lo : hi;
                    clearbit(w == lo ? hi : lo);
                } else if (cm <= 8) {
                    float4 pm = p[m];
                    int rc = gather(m, pm);
                    if (rc >= 0) {
                        float bs = -1.0f; int bi = NN;
                        for (int k2 = 0; k2 < rc; ++k2) {
                            int q = rb[k2]; float sc2 = s_sc[q];
                            if (sc2 > bs || (sc2 == bs && q < bi)) { bs = sc2; bi = q; }
                        }
                        for (int k2 = 0; k2 < rc; ++k2) {
                            int q = rb[k2];
                            if (q != bi) clearbit(q);
                        }
                    } else {
                        float bs = -1.0f; int bi = NN;
                        for (int j = 0; j < NN; ++j) {
                            float4 qq = p[j];
                            float dot = pm.x * qq.x + pm.y * qq.y;
                            float t = pm.z + qq.z;
                            float d2 = fmaf(-2.0f, dot, t);
                            if (d2 < RAD2) { float sc2 = s_sc[j];
                                if (sc2 > bs || (sc2 == bs && j < bi)) { bs = sc2; bi = j; } }
                        }
                        for (int j = 0; j < NN; ++j) {
                            float4 qq = p[j];
                            float dot = pm.x * qq.x + pm.y * qq.y;
                            float t = pm.z + qq.z;
                            float d2 = fmaf(-2.0f, dot, t);
                            if (d2 < RAD2 && j != bi) clearbit(j);
                        }
                    }
                } else {
                    float4 pm = p[m];
                    float bs = -1.0f; int bi = NN;
                    for (int j = 0; j < NN; ++j) {
                        float4 qq = p[j];
                        float dot = pm.x * qq.x + pm.y * qq.y;
                        float t = pm.z + qq.z;
                        float d2 = fmaf(-2.0f, dot, t);
                        if (d2 < RAD2) { float sc2 = s_sc[j];
                            if (sc2 > bs || (sc2 == bs && j < bi)) { bs = sc2; bi = j; } }
                    }
                    for (int j = 0; j < NN; ++j) {
                        float4 qq = p[j];
                        float dot = pm.x * qq.x + pm.y * qq.y;
                        float t = pm.z + qq.z;
                        float d2 = fmaf(-2.0f, dot, t);
                        if (d2 < RAD2 && j != bi) clearbit(j);
                    }
                }
            }
            // my own fate
            for (int k = 0; k < cntm; ++k)
                if (mem[k] == (unsigned short)li) { alive = ((am >> k) & 1ull) != 0; break; }
        }
    }

    // ---- partial sums (this block's 256 points) ----
    int stream = imgid >> 2, b = imgid & 3;
    const float* disp = (stream ? dd1 : dd0) + (size_t)b * NN;
    float sum_dp = 0.f, cnt_p = 0.f, sum_sv = 0.f, cnt_v = 0.f;
    if (alive) {
        float sc = s_sc[li];
        cnt_v = 1.0f; sum_sv = sc;
        if (sc > TH_SCORE) { cnt_p = 1.0f; sum_dp = disp[li]; }
    }
    __syncthreads();
#pragma unroll
    for (int q = 0; q < 4; ++q) {
        float v = (q == 0) ? sum_dp : (q == 1) ? cnt_p : (q == 2) ? sum_sv : cnt_v;
        for (int o = 32; o > 0; o >>= 1) v += __shfl_down(v, o, 64);
        if ((tid & 63) == 0) s_red[tid >> 6] = v;
        __syncthreads();
        if (tid == 0) {
            float r = s_red[0] + s_red[1] + s_red[2] + s_red[3];
            atomicAdd(&acc[stream * 4 + q], r);
        }
        __syncthreads();
    }
}

__global__ void k_final(const float* __restrict__ acc, float* __restrict__ out)
{
    float r = 0.0f;
    for (int s = 0; s < 2; ++s) {
        float sdp = acc[s * 4 + 0], cp = acc[s * 4 + 1];
        float ssv = acc[s * 4 + 2], cv = acc[s * 4 + 3];
        r += sdp / fmaxf(cp, 1.0f) + KPPEN * (ssv / fmaxf(cv, 1.0f));
    }
    out[0] = r;
}

extern "C" void kernel_launch(void* const* d_in, const int* in_sizes, int n_in,
                              void* d_out, int out_size, void* d_ws, size_t ws_size,
                              hipStream_t stream)
{
    const float* lp0 = (const float*)d_in[0];
    const float* lp1 = (const float*)d_in[1];
    const float* kp0 = (const float*)d_in[2];
    const float* kp1 = (const float*)d_in[3];
    const float* dd0 = (const float*)d_in[4];
    const float* dd1 = (const float*)d_in[5];

    char* ws = (char*)d_ws;
    float*          scores  = (float*)(ws + OFF_SCORES);
    float4*         pts     = (float4*)(ws + OFF_PTS);
    unsigned char*  cnt     = (unsigned char*)(ws + OFF_CNT);
    unsigned short* partner = (unsigned short*)(ws + OFF_PARTNER);
    unsigned short* cells   = (unsigned short*)(ws + OFF_CELLS);
    unsigned int*   ccnt    = (unsigned int*)(ws + OFF_CCNT);
    float*          acc     = (float*)(ws + OFF_ACC);

    hipMemsetAsync(ws + OFF_CCNT, 0, 614432, stream);
    k_sample<<<128, 256, 0, stream>>>(lp0, lp1, kp0, kp1, scores, pts, cells, ccnt);
    k_cnt<<<128, 256, 0, stream>>>(pts, cells, ccnt, cnt, partner);
    k_nms<<<128, 256, 0, stream>>>(scores, pts, cnt, partner, cells, ccnt, dd0, dd1, acc);
    k_final<<<1, 1, 0, stream>>>(acc, (float*)d_out);
}

// Round 7
// 116.319 us; speedup vs baseline: 3.8717x; 1.1639x over previous
//
#include <hip/hip_runtime.h>
#include <math.h>

#define NN 4096
#define HH 480
#define WW 640
#define RAD2 4.0f
#define TH_SCORE 0.1f
#define KPPEN -0.001f
#define CXN 160
#define CYN 120
#define NCELL (CXN * CYN)
#define SLOTS 8
#define CAP 48

// ---------------- workspace layout (bytes) ----------------
#define OFF_SCORES  0        // f32 [8][4096]               131072
#define OFF_PTS     131072   // float4 [8][4096]            524288
#define OFF_CNT     655360   // u8  [8][4096]               32768
#define OFF_PARTNER 688128   // u16 [8][4096]               65536
#define OFF_ROWS    753664   // uint4 [8][4096] (8xu16)     524288
#define OFF_CELLS   1277952  // u16 [8][19200][8]           2457600
#define OFF_CCNT    3735552  // u32 [8][19200]              614400
#define OFF_ACC     4349952  // f32 [2][4]                  32
#define OFF_DONE    4349984  // u32                         4
// memset per call: [OFF_CCNT, OFF_DONE+4) = 614436 bytes (contiguous)

__global__ __launch_bounds__(256) void k_sample(
    const float* __restrict__ lp0, const float* __restrict__ lp1,
    const float* __restrict__ kp0, const float* __restrict__ kp1,
    float* __restrict__ scores, float4* __restrict__ pts,
    unsigned short* __restrict__ cells, unsigned int* __restrict__ ccnt)
{
#pragma clang fp contract(off)
    int gid = blockIdx.x * 256 + threadIdx.x;   // 0..32767
    int s = gid >> 14;
    int r = gid & 16383;
    int b = r >> 12;
    const float* kp  = (s ? kp1 : kp0) + (size_t)r * 2;
    const float* img = (s ? lp1 : lp0) + (size_t)b * (HH * WW);
    float px = kp[0], py = kp[1];
    float x = (px + 1.0f) * 0.5f * (float)(WW - 1);
    float y = (py + 1.0f) * 0.5f * (float)(HH - 1);
    float x0 = floorf(x), y0 = floorf(y);
    float wx = x - x0, wy = y - y0;
    int ix0 = (int)fminf(fmaxf(x0, 0.0f), (float)(WW - 1));
    int iy0 = (int)fminf(fmaxf(y0, 0.0f), (float)(HH - 1));
    int ix1 = (int)fminf(fmaxf(x0 + 1.0f, 0.0f), (float)(WW - 1));
    int iy1 = (int)fminf(fmaxf(y0 + 1.0f, 0.0f), (float)(HH - 1));
    float g00 = img[iy0 * WW + ix0];
    float g01 = img[iy0 * WW + ix1];
    float g10 = img[iy1 * WW + ix0];
    float g11 = img[iy1 * WW + ix1];
    float sc = g00 * (1.0f - wx) * (1.0f - wy)
             + g01 * wx * (1.0f - wy)
             + g10 * (1.0f - wx) * wy
             + g11 * wx * wy;
    float xw = (px / 2.0f + 0.5f) * (float)(WW - 1);
    float yw = (py / 2.0f + 0.5f) * (float)(HH - 1);
    float sq = xw * xw + yw * yw;   // mul, mul, add — matches all d2 users
    scores[gid] = sc;
    pts[gid] = make_float4(xw, yw, sq, 0.0f);
    int imgid = gid >> 12;
    int li = gid & (NN - 1);
    int cx = (int)(xw * 0.25f); cx = cx < 0 ? 0 : (cx > CXN - 1 ? CXN - 1 : cx);
    int cy = (int)(yw * 0.25f); cy = cy < 0 ? 0 : (cy > CYN - 1 ? CYN - 1 : cy);
    int cell = imgid * NCELL + cy * CXN + cx;
    unsigned int pos = atomicAdd(&ccnt[cell], 1u);
    if (pos < SLOTS) cells[(size_t)cell * SLOTS + pos] = (unsigned short)li;
}

// One thread per point: count, index-sum (partner), and packed 8-neighbor row.
// 3x3 cells fully unrolled with validity masks => all ccnt loads parallel,
// all cell-list uint4 loads parallel, then candidate pts loads parallel.
__global__ __launch_bounds__(256) void k_cnt(
    const float4* __restrict__ pts, const unsigned short* __restrict__ cells,
    const unsigned int* __restrict__ ccnt,
    unsigned char* __restrict__ cnt, unsigned short* __restrict__ partner,
    uint4* __restrict__ rows4)
{
#pragma clang fp contract(off)
    int gid = blockIdx.x * 256 + threadIdx.x;
    int imgid = gid >> 12;
    int li = gid & (NN - 1);
    const float4* p = pts + ((size_t)imgid << 12);
    float4 a = p[li];
    int cx = (int)(a.x * 0.25f); cx = cx < 0 ? 0 : (cx > CXN - 1 ? CXN - 1 : cx);
    int cy = (int)(a.y * 0.25f); cy = cy < 0 ? 0 : (cy > CYN - 1 ? CYN - 1 : cy);

    int c = 0, sum = 0; bool ov = false;
    unsigned long long rlo = 0ull, rhi = 0ull;
    auto place = [&](int pos, unsigned q) {
        unsigned long long v = (unsigned long long)q;
        switch (pos) {
            case 0: rlo |= v;       break;
            case 1: rlo |= v << 16; break;
            case 2: rlo |= v << 32; break;
            case 3: rlo |= v << 48; break;
            case 4: rhi |= v;       break;
            case 5: rhi |= v << 16; break;
            case 6: rhi |= v << 32; break;
            case 7: rhi |= v << 48; break;
        }
    };
    auto test = [&](unsigned q) {
        float4 qq = p[q];
        float dot = a.x * qq.x + a.y * qq.y;   // mul,mul,add (contract off)
        float t = a.z + qq.z;
        float d2 = fmaf(-2.0f, dot, t);        // == t - 2*dot (2*dot exact)
        if (d2 < RAD2) {
            if (c < 8) place(c, q);
            ++c; sum += (int)q;
        }
    };

#pragma unroll
    for (int dy = -1; dy <= 1; ++dy) {
#pragma unroll
        for (int dx = -1; dx <= 1; ++dx) {
            int yy = cy + dy, xx = cx + dx;
            bool valid = (yy >= 0) & (yy < CYN) & (xx >= 0) & (xx < CXN);
            int cell = imgid * NCELL + (valid ? yy * CXN + xx : 0);
            unsigned n = valid ? ccnt[cell] : 0u;
            if (n > SLOTS) { ov = true; n = SLOTS; }
            uint4 cl = valid ? *(const uint4*)&cells[(size_t)cell * SLOTS]
                             : make_uint4(0, 0, 0, 0);
            unsigned q0 = cl.x & 0xffffu, q1 = cl.x >> 16;
            unsigned q2 = cl.y & 0xffffu, q3 = cl.y >> 16;
            unsigned q4 = cl.z & 0xffffu, q5 = cl.z >> 16;
            unsigned q6 = cl.w & 0xffffu, q7 = cl.w >> 16;
            if (n > 0) test(q0);
            if (n > 1) test(q1);
            if (n > 2) test(q2);
            if (n > 3) test(q3);
            if (n > 4) test(q4);
            if (n > 5) test(q5);
            if (n > 6) test(q6);
            if (n > 7) test(q7);
        }
    }
    if (ov) {   // exact fallback (cell slot overflow; ~never)
        c = 0; sum = 0; rlo = 0ull; rhi = 0ull;
        for (int j = 0; j < NN; ++j) test((unsigned)j);
    }
    cnt[gid] = (unsigned char)(c > 255 ? 255 : c);
    partner[gid] = (unsigned short)((sum - li) & 0xFFFF);  // valid iff c==2
    if (c >= 3 && c <= 8)
        rows4[gid] = make_uint4((unsigned)rlo, (unsigned)(rlo >> 32),
                                (unsigned)rhi, (unsigned)(rhi >> 32));
}

// One THREAD per point. Exact NMS: alive[p] depends only on p's component.
// pair-type -> O(1); residual -> private BFS over precomputed rows + replay.
// Last block computes the final scalar (k_final fused).
__global__ __launch_bounds__(256) void k_nms(
    const float* __restrict__ scoresG, const float4* __restrict__ pts,
    const unsigned char* __restrict__ cntG, const unsigned short* __restrict__ partnerG,
    const uint4* __restrict__ rows4,
    const float* __restrict__ dd0, const float* __restrict__ dd1,
    float* __restrict__ acc, unsigned int* __restrict__ done,
    float* __restrict__ out)
{
#pragma clang fp contract(off)
    __shared__ float          s_sc[NN];          // 16 KB
    __shared__ unsigned char  s_cnt[NN];         // 4 KB
    __shared__ unsigned short s_partner[NN];     // 8 KB
    __shared__ unsigned short s_mem[256][CAP + 2];  // 25.6 KB (pad 25 words)
    __shared__ float s_red[4];

    int imgid = blockIdx.x >> 4;
    int seg = blockIdx.x & 15;
    int base = imgid << 12;
    int tid = threadIdx.x;
    const float4* p = pts + (size_t)base;

    for (int t = tid; t < NN; t += 256) {
        s_sc[t] = scoresG[base + t];
        s_cnt[t] = cntG[base + t];
        s_partner[t] = partnerG[base + t];
    }
    __syncthreads();

    int li = (seg << 8) + tid;
    int c = s_cnt[li];
    bool alive = true;

    if (c >= 2) {
        int pr = s_partner[li];
        if (c == 2 && s_cnt[pr] == 2) {
            int lo = li < pr ? li : pr, hi = li < pr ? pr : li;
            int w = (s_sc[lo] >= s_sc[hi]) ? lo : hi;   // tie -> lower index
            alive = (w == li);
        } else {
            // ---- BFS component over precomputed rows ----
            unsigned short* mem = s_mem[tid];
            int cntm = 1, proc = 0;
            mem[0] = (unsigned short)li;
            auto insert = [&](unsigned q) {
                for (int k = 0; k < cntm; ++k) if (mem[k] == (unsigned short)q) return;
                if (cntm < CAP) mem[cntm++] = (unsigned short)q;
            };
            auto full_insert = [&](int m) {
                float4 pm = p[m];
                for (int j = 0; j < NN; ++j) {
                    float4 qq = p[j];
                    float dot = pm.x * qq.x + pm.y * qq.y;
                    float t = pm.z + qq.z;
                    float d2 = fmaf(-2.0f, dot, t);
                    if (d2 < RAD2) insert((unsigned)j);
                }
            };
            while (proc < cntm) {
                int m = mem[proc++];
                int cm = s_cnt[m];
                if (cm == 2) {
                    insert(s_partner[m]);
                } else if (cm <= 8) {
                    uint4 w = rows4[base + m];
                    unsigned q0 = w.x & 0xffffu, q1 = w.x >> 16;
                    unsigned q2 = w.y & 0xffffu, q3 = w.y >> 16;
                    unsigned q4 = w.z & 0xffffu, q5 = w.z >> 16;
                    unsigned q6 = w.w & 0xffffu, q7 = w.w >> 16;
                    if (cm > 0) insert(q0);
                    if (cm > 1) insert(q1);
                    if (cm > 2) insert(q2);
                    if (cm > 3) insert(q3);
                    if (cm > 4) insert(q4);
                    if (cm > 5) insert(q5);
                    if (cm > 6) insert(q6);
                    if (cm > 7) insert(q7);
                } else {
                    full_insert(m);
                }
            }
            // sort members ascending
            for (int k = 1; k < cntm; ++k) {
                unsigned short v = mem[k]; int j2 = k;
                while (j2 > 0 && mem[j2 - 1] > v) { mem[j2] = mem[j2 - 1]; --j2; }
                mem[j2] = v;
            }
            // ---- ascending replay (exact reference semantics) ----
            unsigned long long am = (cntm >= 64) ? ~0ull : ((1ull << cntm) - 1ull);
            auto clearbit = [&](unsigned q) {
                for (int k = 0; k < cntm; ++k)
                    if (mem[k] == (unsigned short)q) { am &= ~(1ull << k); return; }
            };
            for (int k = 0; k < cntm; ++k) {
                if (!((am >> k) & 1ull)) continue;
                int m = mem[k];
                int cm = s_cnt[m];
                if (cm == 2) {
                    int pr2 = s_partner[m];
                    int lo = m < pr2 ? m : pr2, hi = m < pr2 ? pr2 : m;
                    int w = (s_sc[lo] >= s_sc[hi]) ? lo : hi;
                    clearbit((unsigned)(w == lo ? hi : lo));
                } else if (cm <= 8) {
                    uint4 w = rows4[base + m];
                    unsigned q0 = w.x & 0xffffu, q1 = w.x >> 16;
                    unsigned q2 = w.y & 0xffffu, q3 = w.y >> 16;
                    unsigned q4 = w.z & 0xffffu, q5 = w.z >> 16;
                    unsigned q6 = w.w & 0xffffu, q7 = w.w >> 16;
                    float bs = -1.0f; int bi = NN;
                    auto cand = [&](int k2, unsigned q) {
                        if (k2 < cm) {
                            float s2 = s_sc[q];
                            if (s2 > bs || (s2 == bs && (int)q < bi)) { bs = s2; bi = (int)q; }
                        }
                    };
                    cand(0, q0); cand(1, q1); cand(2, q2); cand(3, q3);
                    cand(4, q4); cand(5, q5); cand(6, q6); cand(7, q7);
                    auto clr = [&](int k2, unsigned q) {
                        if (k2 < cm && (int)q != bi) clearbit(q);
                    };
                    clr(0, q0); clr(1, q1); clr(2, q2); clr(3, q3);
                    clr(4, q4); clr(5, q5); clr(6, q6); clr(7, q7);
                } else {
                    float4 pm = p[m];
                    float bs = -1.0f; int bi = NN;
                    for (int j = 0; j < NN; ++j) {
                        float4 qq = p[j];
                        float dot = pm.x * qq.x + pm.y * qq.y;
                        float t = pm.z + qq.z;
                        float d2 = fmaf(-2.0f, dot, t);
                        if (d2 < RAD2) {
                            float s2 = s_sc[j];
                            if (s2 > bs || (s2 == bs && j < bi)) { bs = s2; bi = j; }
                        }
                    }
                    for (int j = 0; j < NN; ++j) {
                        float4 qq = p[j];
                        float dot = pm.x * qq.x + pm.y * qq.y;
                        float t = pm.z + qq.z;
                        float d2 = fmaf(-2.0f, dot, t);
                        if (d2 < RAD2 && j != bi) clearbit((unsigned)j);
                    }
                }
            }
            for (int k = 0; k < cntm; ++k)
                if (mem[k] == (unsigned short)li) { alive = ((am >> k) & 1ull) != 0; break; }
        }
    }

    // ---- partial sums ----
    int stream = imgid >> 2, b = imgid & 3;
    const float* disp = (stream ? dd1 : dd0) + (size_t)b * NN;
    float sum_dp = 0.f, cnt_p = 0.f, sum_sv = 0.f, cnt_v = 0.f;
    if (alive) {
        float sc = s_sc[li];
        cnt_v = 1.0f; sum_sv = sc;
        if (sc > TH_SCORE) { cnt_p = 1.0f; sum_dp = disp[li]; }
    }
    __syncthreads();
#pragma unroll
    for (int q = 0; q < 4; ++q) {
        float v = (q == 0) ? sum_dp : (q == 1) ? cnt_p : (q == 2) ? sum_sv : cnt_v;
        for (int o = 32; o > 0; o >>= 1) v += __shfl_down(v, o, 64);
        if ((tid & 63) == 0) s_red[tid >> 6] = v;
        __syncthreads();
        if (tid == 0) {
            float r = s_red[0] + s_red[1] + s_red[2] + s_red[3];
            atomicAdd(&acc[stream * 4 + q], r);
        }
        __syncthreads();
    }

    // ---- fused finalization: last of 128 blocks computes the scalar ----
    if (tid == 0) {
        __threadfence();
        unsigned prev = atomicAdd(done, 1u);
        if (prev == 127u) {
            float r = 0.0f;
            for (int s = 0; s < 2; ++s) {
                float sdp = atomicAdd(&acc[s * 4 + 0], 0.0f);
                float cp  = atomicAdd(&acc[s * 4 + 1], 0.0f);
                float ssv = atomicAdd(&acc[s * 4 + 2], 0.0f);
                float cv  = atomicAdd(&acc[s * 4 + 3], 0.0f);
                r += sdp / fmaxf(cp, 1.0f) + KPPEN * (ssv / fmaxf(cv, 1.0f));
            }
            out[0] = r;
        }
    }
}

extern "C" void kernel_launch(void* const* d_in, const int* in_sizes, int n_in,
                              void* d_out, int out_size, void* d_ws, size_t ws_size,
                              hipStream_t stream)
{
    const float* lp0 = (const float*)d_in[0];
    const float* lp1 = (const float*)d_in[1];
    const float* kp0 = (const float*)d_in[2];
    const float* kp1 = (const float*)d_in[3];
    const float* dd0 = (const float*)d_in[4];
    const float* dd1 = (const float*)d_in[5];

    char* ws = (char*)d_ws;
    float*          scores  = (float*)(ws + OFF_SCORES);
    float4*         pts     = (float4*)(ws + OFF_PTS);
    unsigned char*  cnt     = (unsigned char*)(ws + OFF_CNT);
    unsigned short* partner = (unsigned short*)(ws + OFF_PARTNER);
    uint4*          rows4   = (uint4*)(ws + OFF_ROWS);
    unsigned short* cells   = (unsigned short*)(ws + OFF_CELLS);
    unsigned int*   ccnt    = (unsigned int*)(ws + OFF_CCNT);
    float*          acc     = (float*)(ws + OFF_ACC);
    unsigned int*   done    = (unsigned int*)(ws + OFF_DONE);

    hipMemsetAsync(ws + OFF_CCNT, 0, 614436, stream);
    k_sample<<<128, 256, 0, stream>>>(lp0, lp1, kp0, kp1, scores, pts, cells, ccnt);
    k_cnt<<<128, 256, 0, stream>>>(pts, cells, ccnt, cnt, partner, rows4);
    k_nms<<<128, 256, 0, stream>>>(scores, pts, cnt, partner, rows4,
                                   dd0, dd1, acc, done, (float*)d_out);
}